// Round 14
// baseline (413.143 us; speedup 1.0000x reference)
//
#include <hip/hip_runtime.h>
#include <hip/hip_fp16.h>

#define N_NODES 100000
#define N_EDGES 1600000
#define N_GRAPHS 1000
#define FD_IN 9
#define FD_PAD 16
#define HDIM 128
#define NPG 100          // nodes per graph (contiguous, batch = arange(N)//100)
#define BN_EPS 1e-5f
#define ROWCAP 64        // padded adjacency row; P(indeg>64) ~ 1e-18 (Poisson mean 16)

// ---------------- padded-CSR build: one pass, no scan/scatter ----------------
// colp[d][p] = src for p-th in-edge of d. Same 1.6M atomics the old hist paid,
// col write folded into the same kernel.
__global__ void k_build(const int* __restrict__ src, const int* __restrict__ dst,
                        int* __restrict__ cnt, int* __restrict__ colp) {
    int e = blockIdx.x * blockDim.x + threadIdx.x;
    if (e < N_EDGES) {
        int d = dst[e];
        int p = atomicAdd(&cnt[d], 1);
        colp[((size_t)d << 6) + p] = src[e];
    }
}

__global__ void k_dinv(const int* __restrict__ cnt, float* __restrict__ dinv) {
    int v = blockIdx.x * blockDim.x + threadIdx.x;
    if (v < N_NODES) dinv[v] = rsqrtf((float)cnt[v] + 1.0f);
}

// ---------------- layer 1: aggregate x in 9-dim (padded 16) input space ----------------
__global__ __launch_bounds__(256) void k_scale_x(const float* __restrict__ x,
                                                 const float* __restrict__ dinv,
                                                 float* __restrict__ xs) {
    int i = blockIdx.x * blockDim.x + threadIdx.x;   // over N*16
    int v = i >> 4, k = i & 15;
    float val = (k < FD_IN) ? dinv[v] * x[v * FD_IN + k] : 0.f;
    xs[i] = val;
}

__global__ __launch_bounds__(256) void k_agg9(const float* __restrict__ xs,
                                              const int* __restrict__ cnt,
                                              const int* __restrict__ colp,
                                              const float* __restrict__ dinv,
                                              float* __restrict__ aggx) {
    int t = threadIdx.x;
    int v = blockIdx.x * 16 + (t >> 4);
    int f = t & 15;
    float acc = xs[v * FD_PAD + f];                  // self
    int r0 = v << 6;
    int r1 = r0 + cnt[v];
    int i = r0;
    for (; i + 4 <= r1; i += 4) {
        int s0 = colp[i], s1 = colp[i + 1], s2 = colp[i + 2], s3 = colp[i + 3];
        float a0 = xs[s0 * FD_PAD + f];
        float a1 = xs[s1 * FD_PAD + f];
        float a2 = xs[s2 * FD_PAD + f];
        float a3 = xs[s3 * FD_PAD + f];
        acc += (a0 + a1) + (a2 + a3);
    }
    for (; i < r1; ++i) acc += xs[colp[i] * FD_PAD + f];
    aggx[v * FD_PAD + f] = acc * dinv[v];
}

// ---------------- fp16 helpers ----------------
__device__ __forceinline__ float4 h4f(uint2 u) {
    __half2 h0 = *reinterpret_cast<__half2*>(&u.x);
    __half2 h1 = *reinterpret_cast<__half2*>(&u.y);
    float2 f0 = __half22float2(h0);
    float2 f1 = __half22float2(h1);
    return make_float4(f0.x, f0.y, f1.x, f1.y);
}

// ---------------- v2 GEMM body: 32-node hs tile (LDS) x W (LDS-staged K-chunks) ----------
__device__ __forceinline__ void gemm32_body(const float* hs, float* ws,
                                            const float* __restrict__ W,
                                            const float* __restrict__ dinv,
                                            __half2* __restrict__ gh,
                                            int node0, int t) {
    int c4 = (t & 31) * 4;          // 4 output cols
    int g  = t >> 5;                // node group: nodes g*4 .. g*4+3
    float4 a0 = make_float4(0.f, 0.f, 0.f, 0.f);
    float4 a1 = a0, a2 = a0, a3 = a0;
    for (int kc = 0; kc < HDIM; kc += 32) {
        __syncthreads();            // ws safe to overwrite (also covers hs producer)
        for (int i = t * 4; i < 32 * HDIM; i += 1024)
            *(float4*)&ws[i] = *(const float4*)&W[kc * HDIM + i];
        __syncthreads();
#pragma unroll
        for (int k = 0; k < 32; k += 4) {
            const float4 w0 = *(const float4*)&ws[(k + 0) * HDIM + c4];
            const float4 w1 = *(const float4*)&ws[(k + 1) * HDIM + c4];
            const float4 w2 = *(const float4*)&ws[(k + 2) * HDIM + c4];
            const float4 w3 = *(const float4*)&ws[(k + 3) * HDIM + c4];
            const float4 h0 = *(const float4*)&hs[(g * 4 + 0) * HDIM + kc + k];
            const float4 h1 = *(const float4*)&hs[(g * 4 + 1) * HDIM + kc + k];
            const float4 h2 = *(const float4*)&hs[(g * 4 + 2) * HDIM + kc + k];
            const float4 h3 = *(const float4*)&hs[(g * 4 + 3) * HDIM + kc + k];
            a0.x = fmaf(h0.x, w0.x, a0.x); a0.y = fmaf(h0.x, w0.y, a0.y); a0.z = fmaf(h0.x, w0.z, a0.z); a0.w = fmaf(h0.x, w0.w, a0.w);
            a0.x = fmaf(h0.y, w1.x, a0.x); a0.y = fmaf(h0.y, w1.y, a0.y); a0.z = fmaf(h0.y, w1.z, a0.z); a0.w = fmaf(h0.y, w1.w, a0.w);
            a0.x = fmaf(h0.z, w2.x, a0.x); a0.y = fmaf(h0.z, w2.y, a0.y); a0.z = fmaf(h0.z, w2.z, a0.z); a0.w = fmaf(h0.z, w2.w, a0.w);
            a0.x = fmaf(h0.w, w3.x, a0.x); a0.y = fmaf(h0.w, w3.y, a0.y); a0.z = fmaf(h0.w, w3.z, a0.z); a0.w = fmaf(h0.w, w3.w, a0.w);
            a1.x = fmaf(h1.x, w0.x, a1.x); a1.y = fmaf(h1.x, w0.y, a1.y); a1.z = fmaf(h1.x, w0.z, a1.z); a1.w = fmaf(h1.x, w0.w, a1.w);
            a1.x = fmaf(h1.y, w1.x, a1.x); a1.y = fmaf(h1.y, w1.y, a1.y); a1.z = fmaf(h1.y, w1.z, a1.z); a1.w = fmaf(h1.y, w1.w, a1.w);
            a1.x = fmaf(h1.z, w2.x, a1.x); a1.y = fmaf(h1.z, w2.y, a1.y); a1.z = fmaf(h1.z, w2.z, a1.z); a1.w = fmaf(h1.z, w2.w, a1.w);
            a1.x = fmaf(h1.w, w3.x, a1.x); a1.y = fmaf(h1.w, w3.y, a1.y); a1.z = fmaf(h1.w, w3.z, a1.z); a1.w = fmaf(h1.w, w3.w, a1.w);
            a2.x = fmaf(h2.x, w0.x, a2.x); a2.y = fmaf(h2.x, w0.y, a2.y); a2.z = fmaf(h2.x, w0.z, a2.z); a2.w = fmaf(h2.x, w0.w, a2.w);
            a2.x = fmaf(h2.y, w1.x, a2.x); a2.y = fmaf(h2.y, w1.y, a2.y); a2.z = fmaf(h2.y, w1.z, a2.z); a2.w = fmaf(h2.y, w1.w, a2.w);
            a2.x = fmaf(h2.z, w2.x, a2.x); a2.y = fmaf(h2.z, w2.y, a2.y); a2.z = fmaf(h2.z, w2.z, a2.z); a2.w = fmaf(h2.z, w2.w, a2.w);
            a2.x = fmaf(h2.w, w3.x, a2.x); a2.y = fmaf(h2.w, w3.y, a2.y); a2.z = fmaf(h2.w, w3.z, a2.z); a2.w = fmaf(h2.w, w3.w, a2.w);
            a3.x = fmaf(h3.x, w0.x, a3.x); a3.y = fmaf(h3.x, w0.y, a3.y); a3.z = fmaf(h3.x, w0.z, a3.z); a3.w = fmaf(h3.x, w0.w, a3.w);
            a3.x = fmaf(h3.y, w1.x, a3.x); a3.y = fmaf(h3.y, w1.y, a3.y); a3.z = fmaf(h3.y, w1.z, a3.z); a3.w = fmaf(h3.y, w1.w, a3.w);
            a3.x = fmaf(h3.z, w2.x, a3.x); a3.y = fmaf(h3.z, w2.y, a3.y); a3.z = fmaf(h3.z, w2.z, a3.z); a3.w = fmaf(h3.z, w2.w, a3.w);
            a3.x = fmaf(h3.w, w3.x, a3.x); a3.y = fmaf(h3.w, w3.y, a3.y); a3.z = fmaf(h3.w, w3.z, a3.z); a3.w = fmaf(h3.w, w3.w, a3.w);
        }
    }
#pragma unroll
    for (int n = 0; n < 4; n++) {
        float4 a = (n == 0) ? a0 : (n == 1) ? a1 : (n == 2) ? a2 : a3;
        int v = node0 + g * 4 + n;
        float dv = dinv[v];
        __half2 p0 = __float22half2_rn(make_float2(a.x * dv, a.y * dv));
        __half2 p1 = __float22half2_rn(make_float2(a.z * dv, a.w * dv));
        uint2 pk;
        pk.x = *reinterpret_cast<unsigned*>(&p0);
        pk.y = *reinterpret_cast<unsigned*>(&p1);
        *(uint2*)&gh[(size_t)v * 64 + (c4 >> 1)] = pk;
    }
}

// ---------------- fused: h1 = relu(bn1(aggx@W1+b1));  gh = fp16(dinv*(h1@W2)) ----------------
__global__ __launch_bounds__(256) void k_l1_gemm(const float* __restrict__ aggx,
                                                 const float* __restrict__ W1,
                                                 const float* __restrict__ b1,
                                                 const float* __restrict__ bn_g,
                                                 const float* __restrict__ bn_b,
                                                 const float* __restrict__ bn_rm,
                                                 const float* __restrict__ bn_rv,
                                                 const float* __restrict__ W2,
                                                 const float* __restrict__ dinv,
                                                 __half2* __restrict__ gh) {
    __shared__ float hs[32 * HDIM];       // 16 KB h1 tile
    __shared__ float ws[32 * HDIM];       // 16 KB W K-chunk; head doubles as axs in stage 1
    float* axs = ws;                      // 32*FD_PAD floats = 2 KB, dead after stage 1
    int t = threadIdx.x;
    int node0 = blockIdx.x * 32;
    for (int i = t; i < 32 * FD_PAD; i += 256) axs[i] = aggx[(size_t)node0 * FD_PAD + i];
    // stage 1: h1 tile. W1 column in registers (coalesced: f = lane).
    {
        int f = t & 127, vh = t >> 7;
        float w1r[FD_IN];
#pragma unroll
        for (int k = 0; k < FD_IN; k++) w1r[k] = W1[k * HDIM + f];
        float sc = bn_g[f] * rsqrtf(bn_rv[f] + BN_EPS);
        float bbf = bn_b[f], rmf = bn_rm[f], b1f = b1[f];
        __syncthreads();              // axs visible
#pragma unroll
        for (int i = 0; i < 16; i++) {
            int vl = vh + 2 * i;
            float acc = b1f;
#pragma unroll
            for (int k = 0; k < FD_IN; k++) acc = fmaf(axs[vl * FD_PAD + k], w1r[k], acc);
            hs[vl * HDIM + f] = fmaxf((acc - rmf) * sc + bbf, 0.f);
        }
    }
    // stage 2 (body's first syncthreads covers both hs production and axs death)
    gemm32_body(hs, ws, W2, dinv, gh, node0, t);
}

// ---------------- standalone v2 GEMM: gh[v] = fp16(dinv[v] * (h[v] @ W)) ----------------
__global__ __launch_bounds__(256) void k_gemm128(const float* __restrict__ h,
                                                 const float* __restrict__ W,
                                                 const float* __restrict__ dinv,
                                                 __half2* __restrict__ gh) {
    __shared__ float hs[32 * HDIM];   // 16 KB
    __shared__ float ws[32 * HDIM];   // 16 KB
    int t = threadIdx.x;
    int node0 = blockIdx.x * 32;
    for (int i = t * 4; i < 32 * HDIM; i += 1024)
        *(float4*)&hs[i] = *(const float4*)&h[(size_t)node0 * HDIM + i];
    gemm32_body(hs, ws, W, dinv, gh, node0, t);   // first internal sync covers hs staging
}

// ---------------- fp16-table aggregation + bias + BN + ReLU ----------------
__global__ __launch_bounds__(256) void k_aggh(const uint2* __restrict__ g,   // [N][32] uint2 (fp16x4)
                                              const int* __restrict__ cnt,
                                              const int* __restrict__ colp,
                                              const float* __restrict__ dinv,
                                              const float* __restrict__ bias,
                                              const float* __restrict__ bn_g,
                                              const float* __restrict__ bn_b,
                                              const float* __restrict__ bn_rm,
                                              const float* __restrict__ bn_rv,
                                              float* __restrict__ out) {
    int t = threadIdx.x;
    int v = blockIdx.x * 8 + (t >> 5);      // 8 nodes per 256-block
    int q = t & 31;                         // uint2 slot within row
    int f = q * 4;                          // feature base
    float4 acc, acc2;
    {
        float4 s = h4f(g[(size_t)v * 32 + q]);    // self-loop term
        acc = s;
        acc2 = make_float4(0.f, 0.f, 0.f, 0.f);
    }
    int r0 = v << 6;
    int r1 = r0 + cnt[v];
    int i = r0;
    for (; i + 8 <= r1; i += 8) {
        int s0 = colp[i],     s1 = colp[i + 1], s2 = colp[i + 2], s3 = colp[i + 3];
        int s4 = colp[i + 4], s5 = colp[i + 5], s6 = colp[i + 6], s7 = colp[i + 7];
        uint2 u0 = g[(size_t)s0 * 32 + q];
        uint2 u1 = g[(size_t)s1 * 32 + q];
        uint2 u2 = g[(size_t)s2 * 32 + q];
        uint2 u3 = g[(size_t)s3 * 32 + q];
        uint2 u4 = g[(size_t)s4 * 32 + q];
        uint2 u5 = g[(size_t)s5 * 32 + q];
        uint2 u6 = g[(size_t)s6 * 32 + q];
        uint2 u7 = g[(size_t)s7 * 32 + q];
        float4 a0 = h4f(u0), a1 = h4f(u1), a2 = h4f(u2), a3 = h4f(u3);
        float4 a4 = h4f(u4), a5 = h4f(u5), a6 = h4f(u6), a7 = h4f(u7);
        acc.x  += (a0.x + a1.x) + (a2.x + a3.x);
        acc.y  += (a0.y + a1.y) + (a2.y + a3.y);
        acc.z  += (a0.z + a1.z) + (a2.z + a3.z);
        acc.w  += (a0.w + a1.w) + (a2.w + a3.w);
        acc2.x += (a4.x + a5.x) + (a6.x + a7.x);
        acc2.y += (a4.y + a5.y) + (a6.y + a7.y);
        acc2.z += (a4.z + a5.z) + (a6.z + a7.z);
        acc2.w += (a4.w + a5.w) + (a6.w + a7.w);
    }
    if (i + 4 <= r1) {
        int s0 = colp[i], s1 = colp[i + 1], s2 = colp[i + 2], s3 = colp[i + 3];
        uint2 u0 = g[(size_t)s0 * 32 + q];
        uint2 u1 = g[(size_t)s1 * 32 + q];
        uint2 u2 = g[(size_t)s2 * 32 + q];
        uint2 u3 = g[(size_t)s3 * 32 + q];
        float4 a0 = h4f(u0), a1 = h4f(u1), a2 = h4f(u2), a3 = h4f(u3);
        acc.x += (a0.x + a1.x) + (a2.x + a3.x);
        acc.y += (a0.y + a1.y) + (a2.y + a3.y);
        acc.z += (a0.z + a1.z) + (a2.z + a3.z);
        acc.w += (a0.w + a1.w) + (a2.w + a3.w);
        i += 4;
    }
    for (; i < r1; ++i) {
        float4 a = h4f(g[(size_t)colp[i] * 32 + q]);
        acc2.x += a.x; acc2.y += a.y; acc2.z += a.z; acc2.w += a.w;
    }
    acc.x += acc2.x; acc.y += acc2.y; acc.z += acc2.z; acc.w += acc2.w;
    float dv = dinv[v];
    const float4 bi = *(const float4*)&bias[f];
    const float4 bg = *(const float4*)&bn_g[f];
    const float4 bb = *(const float4*)&bn_b[f];
    const float4 rm = *(const float4*)&bn_rm[f];
    const float4 rv = *(const float4*)&bn_rv[f];
    float4 o;
    o.x = fmaxf((fmaf(acc.x, dv, bi.x) - rm.x) * (bg.x * rsqrtf(rv.x + BN_EPS)) + bb.x, 0.f);
    o.y = fmaxf((fmaf(acc.y, dv, bi.y) - rm.y) * (bg.y * rsqrtf(rv.y + BN_EPS)) + bb.y, 0.f);
    o.z = fmaxf((fmaf(acc.z, dv, bi.z) - rm.z) * (bg.z * rsqrtf(rv.z + BN_EPS)) + bb.z, 0.f);
    o.w = fmaxf((fmaf(acc.w, dv, bi.w) - rm.w) * (bg.w * rsqrtf(rv.w + BN_EPS)) + bb.w, 0.f);
    *(float4*)&out[(size_t)v * HDIM + f] = o;
}

// ---------------- fused pool (mean/max per graph) + 3-layer MLP ----------------
__global__ __launch_bounds__(128) void k_pool_mlp(const float* __restrict__ h,
                                                  const float* __restrict__ fw1, const float* __restrict__ fb1,
                                                  const float* __restrict__ fw2, const float* __restrict__ fb2,
                                                  const float* __restrict__ fw3, const float* __restrict__ fb3,
                                                  float* __restrict__ out) {
    __shared__ float zm[HDIM], zx[HDIM], z1[HDIM], z2[64];
    int gr = blockIdx.x;
    int f = threadIdx.x;
    int base = gr * NPG;
    float sum = 0.f, mx = -INFINITY;
    for (int i = 0; i < NPG; i++) {
        float val = h[(size_t)(base + i) * HDIM + f];
        sum += val;
        mx = fmaxf(mx, val);
    }
    zm[f] = sum / (float)NPG;
    zx[f] = mx;
    __syncthreads();
    float acc = fb1[f];
    for (int k = 0; k < HDIM; k++) acc = fmaf(zm[k], fw1[k * HDIM + f], acc);
    for (int k = 0; k < HDIM; k++) acc = fmaf(zx[k], fw1[(HDIM + k) * HDIM + f], acc);
    z1[f] = fmaxf(acc, 0.f);
    __syncthreads();
    if (f < 64) {
        float a2 = fb2[f];
        for (int k = 0; k < HDIM; k++) a2 = fmaf(z1[k], fw2[k * 64 + f], a2);
        z2[f] = fmaxf(a2, 0.f);
    }
    __syncthreads();
    if (f < 2) {
        float a3 = fb3[f];
        for (int k = 0; k < 64; k++) a3 = fmaf(z2[k], fw3[k * 2 + f], a3);
        out[gr * 2 + f] = a3;
    }
}

extern "C" void kernel_launch(void* const* d_in, const int* in_sizes, int n_in,
                              void* d_out, int out_size, void* d_ws, size_t ws_size,
                              hipStream_t stream) {
    const float* x   = (const float*)d_in[0];
    const int*   ei  = (const int*)d_in[1];
    const float* W1  = (const float*)d_in[3];
    const float* b1  = (const float*)d_in[4];
    const float* W2  = (const float*)d_in[5];
    const float* b2  = (const float*)d_in[6];
    const float* W3  = (const float*)d_in[7];
    const float* b3  = (const float*)d_in[8];
    const float* g1  = (const float*)d_in[9];
    const float* be1 = (const float*)d_in[10];
    const float* rm1 = (const float*)d_in[11];
    const float* rv1 = (const float*)d_in[12];
    const float* g2  = (const float*)d_in[13];
    const float* be2 = (const float*)d_in[14];
    const float* rm2 = (const float*)d_in[15];
    const float* rv2 = (const float*)d_in[16];
    const float* g3  = (const float*)d_in[17];
    const float* be3 = (const float*)d_in[18];
    const float* rm3 = (const float*)d_in[19];
    const float* rv3 = (const float*)d_in[20];
    const float* fw1 = (const float*)d_in[21];
    const float* fb1 = (const float*)d_in[22];
    const float* fw2 = (const float*)d_in[23];
    const float* fb2 = (const float*)d_in[24];
    const float* fw3 = (const float*)d_in[25];
    const float* fb3 = (const float*)d_in[26];

    char* ws = (char*)d_ws;
    size_t off = 0;
    auto alloc = [&](size_t bytes) -> void* {
        void* p = ws + off;
        off += (bytes + 255) & ~(size_t)255;
        return p;
    };
    int*     cnt  = (int*)alloc((size_t)N_NODES * 4);
    float*   dinv = (float*)alloc((size_t)N_NODES * 4);
    int*     colp = (int*)alloc((size_t)N_NODES * ROWCAP * 4);   // 25.6 MB
    float*   xs   = (float*)alloc((size_t)N_NODES * FD_PAD * 4); // 6.4 MB
    float*   aggx = (float*)alloc((size_t)N_NODES * FD_PAD * 4); // 6.4 MB
    __half2* gh   = (__half2*)alloc((size_t)N_NODES * HDIM * 2); // 25.6 MB
    float*   hbuf = (float*)alloc((size_t)N_NODES * HDIM * 4);   // 51.2 MB (h1/h2/h3)

    const int* src = ei;
    const int* dst = ei + N_EDGES;

    // ---- padded-CSR build (shared by all 3 conv layers) ----
    hipMemsetAsync(cnt, 0, (size_t)N_NODES * 4, stream);
    k_build<<<(N_EDGES + 255) / 256, 256, 0, stream>>>(src, dst, cnt, colp);
    k_dinv<<<(N_NODES + 255) / 256, 256, 0, stream>>>(cnt, dinv);

    // ---- layer 1 (input-space aggregation) + layer-2 GEMM fused -> fp16 g2 ----
    k_scale_x<<<(N_NODES * FD_PAD) / 256, 256, 0, stream>>>(x, dinv, xs);
    k_agg9<<<N_NODES / 16, 256, 0, stream>>>(xs, cnt, colp, dinv, aggx);
    k_l1_gemm<<<N_NODES / 32, 256, 0, stream>>>(aggx, W1, b1, g1, be1, rm1, rv1,
                                                W2, dinv, gh);
    // ---- layer 2 aggregation: fp16 g2 -> f32 h2 ----
    k_aggh<<<N_NODES / 8, 256, 0, stream>>>((const uint2*)gh, cnt, colp, dinv, b2, g2, be2, rm2, rv2, hbuf);
    // ---- layer 3 GEMM (f32 h2 -> fp16 g3) + aggregation ----
    k_gemm128<<<N_NODES / 32, 256, 0, stream>>>(hbuf, W3, dinv, gh);
    k_aggh<<<N_NODES / 8, 256, 0, stream>>>((const uint2*)gh, cnt, colp, dinv, b3, g3, be3, rm3, rv3, hbuf);
    // ---- pool + MLP head ----
    k_pool_mlp<<<N_GRAPHS, 128, 0, stream>>>(hbuf, fw1, fb1, fw2, fb2, fw3, fb3, (float*)d_out);
}

// Round 15
// 379.426 us; speedup vs baseline: 1.0889x; 1.0889x over previous
//
#include <hip/hip_runtime.h>
#include <hip/hip_fp16.h>

#define N_NODES 100000
#define N_EDGES 1600000
#define N_GRAPHS 1000
#define FD_IN 9
#define FD_PAD 16
#define HDIM 128
#define NPG 100          // nodes per graph (contiguous, batch = arange(N)//100)
#define BN_EPS 1e-5f
#define SCAN_CHUNK 1024

// ---------------- CSR build ----------------
__global__ void k_hist_pe(const int* __restrict__ dst, int* __restrict__ cnt,
                          int* __restrict__ pe) {
    int i = blockIdx.x * blockDim.x + threadIdx.x;
    if (i < N_EDGES) pe[i] = atomicAdd(&cnt[dst[i]], 1);
}

__global__ void k_block_scan(const int* __restrict__ cnt, int* __restrict__ rowptr,
                             int* __restrict__ partials, float* __restrict__ dinv) {
    __shared__ int sums[256];
    int t = threadIdx.x;
    int idx = blockIdx.x * SCAN_CHUNK + t * 4;
    int v0 = 0, v1 = 0, v2 = 0, v3 = 0;
    if (idx + 3 < N_NODES) {
        int4 c = *(const int4*)&cnt[idx];
        v0 = c.x; v1 = c.y; v2 = c.z; v3 = c.w;
    } else {
        if (idx + 0 < N_NODES) v0 = cnt[idx + 0];
        if (idx + 1 < N_NODES) v1 = cnt[idx + 1];
        if (idx + 2 < N_NODES) v2 = cnt[idx + 2];
        if (idx + 3 < N_NODES) v3 = cnt[idx + 3];
    }
    int s = v0 + v1 + v2 + v3;
    sums[t] = s;
    __syncthreads();
    for (int off = 1; off < 256; off <<= 1) {
        int val = (t >= off) ? sums[t - off] : 0;
        __syncthreads();
        sums[t] += val;
        __syncthreads();
    }
    int excl = sums[t] - s;
    if (t == 255) partials[blockIdx.x] = sums[255];
    if (idx + 0 < N_NODES) { rowptr[idx + 0] = excl;                dinv[idx + 0] = rsqrtf((float)v0 + 1.0f); }
    if (idx + 1 < N_NODES) { rowptr[idx + 1] = excl + v0;           dinv[idx + 1] = rsqrtf((float)v1 + 1.0f); }
    if (idx + 2 < N_NODES) { rowptr[idx + 2] = excl + v0 + v1;      dinv[idx + 2] = rsqrtf((float)v2 + 1.0f); }
    if (idx + 3 < N_NODES) { rowptr[idx + 3] = excl + v0 + v1 + v2; dinv[idx + 3] = rsqrtf((float)v3 + 1.0f); }
}

__global__ void k_partial_scan(int* __restrict__ partials, int nb) {
    __shared__ int s[256];
    int t = threadIdx.x;
    int mine = (t < nb) ? partials[t] : 0;
    s[t] = mine;
    __syncthreads();
    for (int off = 1; off < 256; off <<= 1) {
        int val = (t >= off) ? s[t - off] : 0;
        __syncthreads();
        s[t] += val;
        __syncthreads();
    }
    if (t < nb) partials[t] = s[t] - mine;
    if (t == nb - 1) partials[nb] = s[t];
}

__global__ void k_add_offsets(int* __restrict__ rowptr, const int* __restrict__ partials,
                              int nb) {
    int i = blockIdx.x * blockDim.x + threadIdx.x;
    if (i < N_NODES) rowptr[i] = rowptr[i] + partials[i >> 10];
    if (i == 0) rowptr[N_NODES] = partials[nb];
}

// atomic-free scatter: position precomputed in pe[]
__global__ void k_scatter(const int* __restrict__ src, const int* __restrict__ dst,
                          const int* __restrict__ rowptr, const int* __restrict__ pe,
                          int* __restrict__ col) {
    int e = blockIdx.x * blockDim.x + threadIdx.x;
    if (e < N_EDGES) col[rowptr[dst[e]] + pe[e]] = src[e];
}

// ---------------- layer 1: aggregate x in 9-dim (padded 16) input space ----------------
__global__ __launch_bounds__(256) void k_scale_x(const float* __restrict__ x,
                                                 const float* __restrict__ dinv,
                                                 float* __restrict__ xs) {
    int i = blockIdx.x * blockDim.x + threadIdx.x;   // over N*16
    int v = i >> 4, k = i & 15;
    float val = (k < FD_IN) ? dinv[v] * x[v * FD_IN + k] : 0.f;
    xs[i] = val;
}

__global__ __launch_bounds__(256) void k_agg9(const float* __restrict__ xs,
                                              const int* __restrict__ rowptr,
                                              const int* __restrict__ col,
                                              const float* __restrict__ dinv,
                                              float* __restrict__ aggx) {
    int t = threadIdx.x;
    int v = blockIdx.x * 16 + (t >> 4);
    int f = t & 15;
    float acc = xs[v * FD_PAD + f];                  // self
    int r0 = rowptr[v], r1 = rowptr[v + 1];
    int i = r0;
    for (; i + 4 <= r1; i += 4) {
        int s0 = col[i], s1 = col[i + 1], s2 = col[i + 2], s3 = col[i + 3];
        float a0 = xs[s0 * FD_PAD + f];
        float a1 = xs[s1 * FD_PAD + f];
        float a2 = xs[s2 * FD_PAD + f];
        float a3 = xs[s3 * FD_PAD + f];
        acc += (a0 + a1) + (a2 + a3);
    }
    for (; i < r1; ++i) acc += xs[col[i] * FD_PAD + f];
    aggx[v * FD_PAD + f] = acc * dinv[v];
}

// ---------------- fp16 helpers ----------------
__device__ __forceinline__ float4 h4f(uint2 u) {
    __half2 h0 = *reinterpret_cast<__half2*>(&u.x);
    __half2 h1 = *reinterpret_cast<__half2*>(&u.y);
    float2 f0 = __half22float2(h0);
    float2 f1 = __half22float2(h1);
    return make_float4(f0.x, f0.y, f1.x, f1.y);
}

// ---------------- v3 GEMM body: reg double-buffered W staging ----------------
// Prefetch next 32x128 W chunk into 4xfloat4 regs right after the post-stage
// barrier -> global latency hidden under current chunk's 512 FMAs.
__device__ __forceinline__ void gemm32_body(const float* hs, float* ws,
                                            const float* __restrict__ W,
                                            const float* __restrict__ dinv,
                                            __half2* __restrict__ gh,
                                            int node0, int t) {
    int c4 = (t & 31) * 4;          // 4 output cols
    int g  = t >> 5;                // node group: nodes g*4 .. g*4+3
    float4 a0 = make_float4(0.f, 0.f, 0.f, 0.f);
    float4 a1 = a0, a2 = a0, a3 = a0;
    float4 r0 = *(const float4*)&W[t * 4];
    float4 r1 = *(const float4*)&W[t * 4 + 1024];
    float4 r2 = *(const float4*)&W[t * 4 + 2048];
    float4 r3 = *(const float4*)&W[t * 4 + 3072];
    for (int kc = 0; kc < HDIM; kc += 32) {
        __syncthreads();            // ws free (prev compute done; also covers hs producer)
        *(float4*)&ws[t * 4]        = r0;
        *(float4*)&ws[t * 4 + 1024] = r1;
        *(float4*)&ws[t * 4 + 2048] = r2;
        *(float4*)&ws[t * 4 + 3072] = r3;
        __syncthreads();
        if (kc + 32 < HDIM) {       // prefetch next chunk (hidden under FMAs below)
            const float* Wn = &W[(kc + 32) * HDIM];
            r0 = *(const float4*)&Wn[t * 4];
            r1 = *(const float4*)&Wn[t * 4 + 1024];
            r2 = *(const float4*)&Wn[t * 4 + 2048];
            r3 = *(const float4*)&Wn[t * 4 + 3072];
        }
#pragma unroll
        for (int k = 0; k < 32; k += 4) {
            const float4 w0 = *(const float4*)&ws[(k + 0) * HDIM + c4];
            const float4 w1 = *(const float4*)&ws[(k + 1) * HDIM + c4];
            const float4 w2 = *(const float4*)&ws[(k + 2) * HDIM + c4];
            const float4 w3 = *(const float4*)&ws[(k + 3) * HDIM + c4];
            const float4 h0 = *(const float4*)&hs[(g * 4 + 0) * HDIM + kc + k];
            const float4 h1 = *(const float4*)&hs[(g * 4 + 1) * HDIM + kc + k];
            const float4 h2 = *(const float4*)&hs[(g * 4 + 2) * HDIM + kc + k];
            const float4 h3 = *(const float4*)&hs[(g * 4 + 3) * HDIM + kc + k];
            a0.x = fmaf(h0.x, w0.x, a0.x); a0.y = fmaf(h0.x, w0.y, a0.y); a0.z = fmaf(h0.x, w0.z, a0.z); a0.w = fmaf(h0.x, w0.w, a0.w);
            a0.x = fmaf(h0.y, w1.x, a0.x); a0.y = fmaf(h0.y, w1.y, a0.y); a0.z = fmaf(h0.y, w1.z, a0.z); a0.w = fmaf(h0.y, w1.w, a0.w);
            a0.x = fmaf(h0.z, w2.x, a0.x); a0.y = fmaf(h0.z, w2.y, a0.y); a0.z = fmaf(h0.z, w2.z, a0.z); a0.w = fmaf(h0.z, w2.w, a0.w);
            a0.x = fmaf(h0.w, w3.x, a0.x); a0.y = fmaf(h0.w, w3.y, a0.y); a0.z = fmaf(h0.w, w3.z, a0.z); a0.w = fmaf(h0.w, w3.w, a0.w);
            a1.x = fmaf(h1.x, w0.x, a1.x); a1.y = fmaf(h1.x, w0.y, a1.y); a1.z = fmaf(h1.x, w0.z, a1.z); a1.w = fmaf(h1.x, w0.w, a1.w);
            a1.x = fmaf(h1.y, w1.x, a1.x); a1.y = fmaf(h1.y, w1.y, a1.y); a1.z = fmaf(h1.y, w1.z, a1.z); a1.w = fmaf(h1.y, w1.w, a1.w);
            a1.x = fmaf(h1.z, w2.x, a1.x); a1.y = fmaf(h1.z, w2.y, a1.y); a1.z = fmaf(h1.z, w2.z, a1.z); a1.w = fmaf(h1.z, w2.w, a1.w);
            a1.x = fmaf(h1.w, w3.x, a1.x); a1.y = fmaf(h1.w, w3.y, a1.y); a1.z = fmaf(h1.w, w3.z, a1.z); a1.w = fmaf(h1.w, w3.w, a1.w);
            a2.x = fmaf(h2.x, w0.x, a2.x); a2.y = fmaf(h2.x, w0.y, a2.y); a2.z = fmaf(h2.x, w0.z, a2.z); a2.w = fmaf(h2.x, w0.w, a2.w);
            a2.x = fmaf(h2.y, w1.x, a2.x); a2.y = fmaf(h2.y, w1.y, a2.y); a2.z = fmaf(h2.y, w1.z, a2.z); a2.w = fmaf(h2.y, w1.w, a2.w);
            a2.x = fmaf(h2.z, w2.x, a2.x); a2.y = fmaf(h2.z, w2.y, a2.y); a2.z = fmaf(h2.z, w2.z, a2.z); a2.w = fmaf(h2.z, w2.w, a2.w);
            a2.x = fmaf(h2.w, w3.x, a2.x); a2.y = fmaf(h2.w, w3.y, a2.y); a2.z = fmaf(h2.w, w3.z, a2.z); a2.w = fmaf(h2.w, w3.w, a2.w);
            a3.x = fmaf(h3.x, w0.x, a3.x); a3.y = fmaf(h3.x, w0.y, a3.y); a3.z = fmaf(h3.x, w0.z, a3.z); a3.w = fmaf(h3.x, w0.w, a3.w);
            a3.x = fmaf(h3.y, w1.x, a3.x); a3.y = fmaf(h3.y, w1.y, a3.y); a3.z = fmaf(h3.y, w1.z, a3.z); a3.w = fmaf(h3.y, w1.w, a3.w);
            a3.x = fmaf(h3.z, w2.x, a3.x); a3.y = fmaf(h3.z, w2.y, a3.y); a3.z = fmaf(h3.z, w2.z, a3.z); a3.w = fmaf(h3.z, w2.w, a3.w);
            a3.x = fmaf(h3.w, w3.x, a3.x); a3.y = fmaf(h3.w, w3.y, a3.y); a3.z = fmaf(h3.w, w3.z, a3.z); a3.w = fmaf(h3.w, w3.w, a3.w);
        }
    }
#pragma unroll
    for (int n = 0; n < 4; n++) {
        float4 a = (n == 0) ? a0 : (n == 1) ? a1 : (n == 2) ? a2 : a3;
        int v = node0 + g * 4 + n;
        float dv = dinv[v];
        __half2 p0 = __float22half2_rn(make_float2(a.x * dv, a.y * dv));
        __half2 p1 = __float22half2_rn(make_float2(a.z * dv, a.w * dv));
        uint2 pk;
        pk.x = *reinterpret_cast<unsigned*>(&p0);
        pk.y = *reinterpret_cast<unsigned*>(&p1);
        *(uint2*)&gh[(size_t)v * 64 + (c4 >> 1)] = pk;
    }
}

// ---------------- fused: h1 = relu(bn1(aggx@W1+b1));  gh = fp16(dinv*(h1@W2)) ----------------
// LDS 32KB (axs unioned into ws; W1 register-cached).
__global__ __launch_bounds__(256) void k_l1_gemm(const float* __restrict__ aggx,
                                                 const float* __restrict__ W1,
                                                 const float* __restrict__ b1,
                                                 const float* __restrict__ bn_g,
                                                 const float* __restrict__ bn_b,
                                                 const float* __restrict__ bn_rm,
                                                 const float* __restrict__ bn_rv,
                                                 const float* __restrict__ W2,
                                                 const float* __restrict__ dinv,
                                                 __half2* __restrict__ gh) {
    __shared__ float hs[32 * HDIM];       // 16 KB h1 tile
    __shared__ float ws[32 * HDIM];       // 16 KB W K-chunk; head doubles as axs in stage 1
    float* axs = ws;                      // 2 KB, dead after stage 1
    int t = threadIdx.x;
    int node0 = blockIdx.x * 32;
    for (int i = t; i < 32 * FD_PAD; i += 256) axs[i] = aggx[(size_t)node0 * FD_PAD + i];
    // stage 1: h1 tile. W1 column in registers (coalesced: f = lane).
    {
        int f = t & 127, vh = t >> 7;
        float w1r[FD_IN];
#pragma unroll
        for (int k = 0; k < FD_IN; k++) w1r[k] = W1[k * HDIM + f];
        float sc = bn_g[f] * rsqrtf(bn_rv[f] + BN_EPS);
        float bbf = bn_b[f], rmf = bn_rm[f], b1f = b1[f];
        __syncthreads();              // axs visible
#pragma unroll
        for (int i = 0; i < 16; i++) {
            int vl = vh + 2 * i;
            float acc = b1f;
#pragma unroll
            for (int k = 0; k < FD_IN; k++) acc = fmaf(axs[vl * FD_PAD + k], w1r[k], acc);
            hs[vl * HDIM + f] = fmaxf((acc - rmf) * sc + bbf, 0.f);
        }
    }
    // stage 2 (body's first syncthreads covers hs production and axs death)
    gemm32_body(hs, ws, W2, dinv, gh, node0, t);
}

// ---------------- standalone v3 GEMM: gh[v] = fp16(dinv[v] * (h[v] @ W)) ----------------
__global__ __launch_bounds__(256) void k_gemm128(const float* __restrict__ h,
                                                 const float* __restrict__ W,
                                                 const float* __restrict__ dinv,
                                                 __half2* __restrict__ gh) {
    __shared__ float hs[32 * HDIM];   // 16 KB
    __shared__ float ws[32 * HDIM];   // 16 KB
    int t = threadIdx.x;
    int node0 = blockIdx.x * 32;
    for (int i = t * 4; i < 32 * HDIM; i += 1024)
        *(float4*)&hs[i] = *(const float4*)&h[(size_t)node0 * HDIM + i];
    gemm32_body(hs, ws, W, dinv, gh, node0, t);   // first internal sync covers hs staging
}

// ---------------- fp16-table aggregation + bias + BN + ReLU ----------------
__global__ __launch_bounds__(256) void k_aggh(const uint2* __restrict__ g,   // [N][32] uint2 (fp16x4)
                                              const int* __restrict__ rowptr,
                                              const int* __restrict__ col,
                                              const float* __restrict__ dinv,
                                              const float* __restrict__ bias,
                                              const float* __restrict__ bn_g,
                                              const float* __restrict__ bn_b,
                                              const float* __restrict__ bn_rm,
                                              const float* __restrict__ bn_rv,
                                              float* __restrict__ out) {
    int t = threadIdx.x;
    int v = blockIdx.x * 8 + (t >> 5);      // 8 nodes per 256-block
    int q = t & 31;                         // uint2 slot within row
    int f = q * 4;                          // feature base
    float4 acc, acc2;
    {
        float4 s = h4f(g[(size_t)v * 32 + q]);    // self-loop term
        acc = s;
        acc2 = make_float4(0.f, 0.f, 0.f, 0.f);
    }
    int r0 = rowptr[v], r1 = rowptr[v + 1];
    int i = r0;
    for (; i + 8 <= r1; i += 8) {
        int s0 = col[i],     s1 = col[i + 1], s2 = col[i + 2], s3 = col[i + 3];
        int s4 = col[i + 4], s5 = col[i + 5], s6 = col[i + 6], s7 = col[i + 7];
        uint2 u0 = g[(size_t)s0 * 32 + q];
        uint2 u1 = g[(size_t)s1 * 32 + q];
        uint2 u2 = g[(size_t)s2 * 32 + q];
        uint2 u3 = g[(size_t)s3 * 32 + q];
        uint2 u4 = g[(size_t)s4 * 32 + q];
        uint2 u5 = g[(size_t)s5 * 32 + q];
        uint2 u6 = g[(size_t)s6 * 32 + q];
        uint2 u7 = g[(size_t)s7 * 32 + q];
        float4 a0 = h4f(u0), a1 = h4f(u1), a2 = h4f(u2), a3 = h4f(u3);
        float4 a4 = h4f(u4), a5 = h4f(u5), a6 = h4f(u6), a7 = h4f(u7);
        acc.x  += (a0.x + a1.x) + (a2.x + a3.x);
        acc.y  += (a0.y + a1.y) + (a2.y + a3.y);
        acc.z  += (a0.z + a1.z) + (a2.z + a3.z);
        acc.w  += (a0.w + a1.w) + (a2.w + a3.w);
        acc2.x += (a4.x + a5.x) + (a6.x + a7.x);
        acc2.y += (a4.y + a5.y) + (a6.y + a7.y);
        acc2.z += (a4.z + a5.z) + (a6.z + a7.z);
        acc2.w += (a4.w + a5.w) + (a6.w + a7.w);
    }
    if (i + 4 <= r1) {
        int s0 = col[i], s1 = col[i + 1], s2 = col[i + 2], s3 = col[i + 3];
        uint2 u0 = g[(size_t)s0 * 32 + q];
        uint2 u1 = g[(size_t)s1 * 32 + q];
        uint2 u2 = g[(size_t)s2 * 32 + q];
        uint2 u3 = g[(size_t)s3 * 32 + q];
        float4 a0 = h4f(u0), a1 = h4f(u1), a2 = h4f(u2), a3 = h4f(u3);
        acc.x += (a0.x + a1.x) + (a2.x + a3.x);
        acc.y += (a0.y + a1.y) + (a2.y + a3.y);
        acc.z += (a0.z + a1.z) + (a2.z + a3.z);
        acc.w += (a0.w + a1.w) + (a2.w + a3.w);
        i += 4;
    }
    for (; i < r1; ++i) {
        float4 a = h4f(g[(size_t)col[i] * 32 + q]);
        acc2.x += a.x; acc2.y += a.y; acc2.z += a.z; acc2.w += a.w;
    }
    acc.x += acc2.x; acc.y += acc2.y; acc.z += acc2.z; acc.w += acc2.w;
    float dv = dinv[v];
    const float4 bi = *(const float4*)&bias[f];
    const float4 bg = *(const float4*)&bn_g[f];
    const float4 bb = *(const float4*)&bn_b[f];
    const float4 rm = *(const float4*)&bn_rm[f];
    const float4 rv = *(const float4*)&bn_rv[f];
    float4 o;
    o.x = fmaxf((fmaf(acc.x, dv, bi.x) - rm.x) * (bg.x * rsqrtf(rv.x + BN_EPS)) + bb.x, 0.f);
    o.y = fmaxf((fmaf(acc.y, dv, bi.y) - rm.y) * (bg.y * rsqrtf(rv.y + BN_EPS)) + bb.y, 0.f);
    o.z = fmaxf((fmaf(acc.z, dv, bi.z) - rm.z) * (bg.z * rsqrtf(rv.z + BN_EPS)) + bb.z, 0.f);
    o.w = fmaxf((fmaf(acc.w, dv, bi.w) - rm.w) * (bg.w * rsqrtf(rv.w + BN_EPS)) + bb.w, 0.f);
    *(float4*)&out[(size_t)v * HDIM + f] = o;
}

// ---------------- fused pool (mean/max per graph) + 3-layer MLP ----------------
__global__ __launch_bounds__(128) void k_pool_mlp(const float* __restrict__ h,
                                                  const float* __restrict__ fw1, const float* __restrict__ fb1,
                                                  const float* __restrict__ fw2, const float* __restrict__ fb2,
                                                  const float* __restrict__ fw3, const float* __restrict__ fb3,
                                                  float* __restrict__ out) {
    __shared__ float zm[HDIM], zx[HDIM], z1[HDIM], z2[64];
    int gr = blockIdx.x;
    int f = threadIdx.x;
    int base = gr * NPG;
    float sum = 0.f, mx = -INFINITY;
    for (int i = 0; i < NPG; i++) {
        float val = h[(size_t)(base + i) * HDIM + f];
        sum += val;
        mx = fmaxf(mx, val);
    }
    zm[f] = sum / (float)NPG;
    zx[f] = mx;
    __syncthreads();
    float acc = fb1[f];
    for (int k = 0; k < HDIM; k++) acc = fmaf(zm[k], fw1[k * HDIM + f], acc);
    for (int k = 0; k < HDIM; k++) acc = fmaf(zx[k], fw1[(HDIM + k) * HDIM + f], acc);
    z1[f] = fmaxf(acc, 0.f);
    __syncthreads();
    if (f < 64) {
        float a2 = fb2[f];
        for (int k = 0; k < HDIM; k++) a2 = fmaf(z1[k], fw2[k * 64 + f], a2);
        z2[f] = fmaxf(a2, 0.f);
    }
    __syncthreads();
    if (f < 2) {
        float a3 = fb3[f];
        for (int k = 0; k < 64; k++) a3 = fmaf(z2[k], fw3[k * 2 + f], a3);
        out[gr * 2 + f] = a3;
    }
}

extern "C" void kernel_launch(void* const* d_in, const int* in_sizes, int n_in,
                              void* d_out, int out_size, void* d_ws, size_t ws_size,
                              hipStream_t stream) {
    const float* x   = (const float*)d_in[0];
    const int*   ei  = (const int*)d_in[1];
    const float* W1  = (const float*)d_in[3];
    const float* b1  = (const float*)d_in[4];
    const float* W2  = (const float*)d_in[5];
    const float* b2  = (const float*)d_in[6];
    const float* W3  = (const float*)d_in[7];
    const float* b3  = (const float*)d_in[8];
    const float* g1  = (const float*)d_in[9];
    const float* be1 = (const float*)d_in[10];
    const float* rm1 = (const float*)d_in[11];
    const float* rv1 = (const float*)d_in[12];
    const float* g2  = (const float*)d_in[13];
    const float* be2 = (const float*)d_in[14];
    const float* rm2 = (const float*)d_in[15];
    const float* rv2 = (const float*)d_in[16];
    const float* g3  = (const float*)d_in[17];
    const float* be3 = (const float*)d_in[18];
    const float* rm3 = (const float*)d_in[19];
    const float* rv3 = (const float*)d_in[20];
    const float* fw1 = (const float*)d_in[21];
    const float* fb1 = (const float*)d_in[22];
    const float* fw2 = (const float*)d_in[23];
    const float* fb2 = (const float*)d_in[24];
    const float* fw3 = (const float*)d_in[25];
    const float* fb3 = (const float*)d_in[26];

    char* ws = (char*)d_ws;
    size_t off = 0;
    auto alloc = [&](size_t bytes) -> void* {
        void* p = ws + off;
        off += (bytes + 255) & ~(size_t)255;
        return p;
    };
    int*   cnt      = (int*)alloc((size_t)N_NODES * 4);
    int*   rowptr   = (int*)alloc(((size_t)N_NODES + 1) * 4);
    int*   partials = (int*)alloc(256 * 4);
    float* dinv     = (float*)alloc((size_t)N_NODES * 4);
    int*   col      = (int*)alloc((size_t)N_EDGES * 4);
    int*   pe       = (int*)alloc((size_t)N_EDGES * 4);
    float* bufA     = (float*)alloc((size_t)N_NODES * HDIM * 4);
    float* bufB     = (float*)alloc((size_t)N_NODES * HDIM * 4);
    // aliases:
    //  xs   <- pe (dead after scatter)
    //  aggx <- bufA[0 : N*16 floats]
    //  gh   <- bufA + 6.4MB (disjoint from aggx; l1_gemm reads aggx, writes gh)
    //  h2/h3 <- bufB
    float*   xs   = (float*)pe;
    float*   aggx = bufA;
    __half2* gh   = (__half2*)(bufA + (size_t)N_NODES * FD_PAD);

    const int* src = ei;
    const int* dst = ei + N_EDGES;

    // ---- CSR build (shared by all 3 conv layers) ----
    hipMemsetAsync(cnt, 0, (size_t)N_NODES * 4, stream);
    k_hist_pe<<<(N_EDGES + 255) / 256, 256, 0, stream>>>(dst, cnt, pe);
    int nb = (N_NODES + SCAN_CHUNK - 1) / SCAN_CHUNK;
    k_block_scan<<<nb, 256, 0, stream>>>(cnt, rowptr, partials, dinv);
    k_partial_scan<<<1, 256, 0, stream>>>(partials, nb);
    k_add_offsets<<<(N_NODES + 255) / 256, 256, 0, stream>>>(rowptr, partials, nb);
    k_scatter<<<(N_EDGES + 255) / 256, 256, 0, stream>>>(src, dst, rowptr, pe, col);

    // ---- layer 1 (input-space aggregation) + layer-2 GEMM fused -> fp16 g2 ----
    k_scale_x<<<(N_NODES * FD_PAD) / 256, 256, 0, stream>>>(x, dinv, xs);
    k_agg9<<<N_NODES / 16, 256, 0, stream>>>(xs, rowptr, col, dinv, aggx);
    k_l1_gemm<<<N_NODES / 32, 256, 0, stream>>>(aggx, W1, b1, g1, be1, rm1, rv1,
                                                W2, dinv, gh);
    // ---- layer 2 aggregation: fp16 g2 -> f32 h2 ----
    k_aggh<<<N_NODES / 8, 256, 0, stream>>>((const uint2*)gh, rowptr, col, dinv, b2, g2, be2, rm2, rv2, bufB);
    // ---- layer 3 GEMM (f32 h2 -> fp16 g3) + aggregation ----
    k_gemm128<<<N_NODES / 32, 256, 0, stream>>>(bufB, W3, dinv, gh);
    k_aggh<<<N_NODES / 8, 256, 0, stream>>>((const uint2*)gh, rowptr, col, dinv, b3, g3, be3, rm3, rv3, bufB);
    // ---- pool + MLP head ----
    k_pool_mlp<<<N_GRAPHS, 128, 0, stream>>>(bufB, fw1, fb1, fw2, fb2, fw3, fb3, (float*)d_out);
}